// Round 8
// baseline (269.337 us; speedup 1.0000x reference)
//
#include <hip/hip_runtime.h>
#include <hip/hip_bf16.h>
#include <math.h>

#define NTOT  8192
#define DIM   512
#define BATCH (NTOT/2)
#define TEMP_INV 5.0f   // 1/0.2
#define TTILE 64                      // 8192 / 128 tiles per side
#define NBLK  (TTILE*(TTILE+1)/2)     // 2080 upper-triangle tiles
#define GKCH  8                       // gram split-K chunks (1024 each)

typedef __attribute__((ext_vector_type(8))) short bf16x8;
typedef __attribute__((ext_vector_type(4))) float f32x4;

// column-major triangle decode: t = bj*(bj+1)/2 + bi, bi <= bj.
__device__ __forceinline__ void decode_tile(int t, int& bi, int& bj)
{
    int b = (int)((sqrtf(8.0f * (float)t + 1.0f) - 1.0f) * 0.5f);
    while ((b + 1) * (b + 2) / 2 <= t) ++b;
    while (b * (b + 1) / 2 > t)       --b;
    bj = b;
    bi = t - b * (b + 1) / 2;
}

__device__ __forceinline__ unsigned int pack_bf16_2(float a, float b)
{
    __hip_bfloat16 ha = __float2bfloat16(a), hb = __float2bfloat16(b);
    unsigned short ua, ub;
    __builtin_memcpy(&ua, &ha, 2); __builtin_memcpy(&ub, &hb, 2);
    return (unsigned int)ua | ((unsigned int)ub << 16);
}
__device__ __forceinline__ float us2f(unsigned short u)
{
    __hip_bfloat16 h; __builtin_memcpy(&h, &u, 2);
    return __bfloat162float(h);
}

// ---------------- fused: normalize + transpose + colsum S ----------------
// 256 blocks x 32 rows. LDS tile row-major [32][516] (pad 4 elems: column
// reads then alias only 2-way across the 4 row-subgroups -> free).
__global__ __launch_bounds__(256)
void norm_trans_k(const float* __restrict__ z,
                  __hip_bfloat16* __restrict__ zn,
                  __hip_bfloat16* __restrict__ znT,
                  float* __restrict__ S)
{
    __shared__ unsigned short tile[32][516];
    const int t = threadIdx.x, lane = t & 63, wave = t >> 6;
    const int r0 = blockIdx.x * 32;

    #pragma unroll
    for (int rr = 0; rr < 8; ++rr) {
        const int lrow = wave * 8 + rr;          // 0..31
        const int row  = r0 + lrow;
        const float4* zr = (const float4*)(z + (size_t)row * DIM);
        const float4 a = zr[lane * 2];
        const float4 b = zr[lane * 2 + 1];
        float ss = a.x*a.x + a.y*a.y + a.z*a.z + a.w*a.w
                 + b.x*b.x + b.y*b.y + b.z*b.z + b.w*b.w;
        #pragma unroll
        for (int off = 1; off < 64; off <<= 1) ss += __shfl_xor(ss, off);
        const float inv = 1.0f / fmaxf(sqrtf(ss), 1e-12f);
        uint4 o;
        o.x = pack_bf16_2(a.x * inv, a.y * inv);
        o.y = pack_bf16_2(a.z * inv, a.w * inv);
        o.z = pack_bf16_2(b.x * inv, b.y * inv);
        o.w = pack_bf16_2(b.z * inv, b.w * inv);
        *(uint4*)(zn + (size_t)row * DIM + lane * 8) = o;
        *(uint4*)&tile[lrow][lane * 8] = o;
    }
    __syncthreads();

    #pragma unroll
    for (int p = 0; p < 8; ++p) {
        const int d  = p * 64 + (t >> 2);        // dim 0..511
        const int rw = (t & 3) * 8;              // local row base
        unsigned short v[8];
        float s = 0.f;
        #pragma unroll
        for (int e = 0; e < 8; ++e) {
            v[e] = tile[rw + e][d];
            s += us2f(v[e]);
        }
        bf16x8 w;
        #pragma unroll
        for (int e = 0; e < 8; ++e) w[e] = (short)v[e];
        *(bf16x8*)(znT + (size_t)d * NTOT + r0 + rw) = w;
        s += __shfl_xor(s, 1);
        s += __shfl_xor(s, 2);
        if ((t & 3) == 0) atomicAdd(&S[d], s);
    }
}

// ---------------- Gram: G32 += znT(:,chunk) znT(:,chunk)^T (fp32 atomics) ----------------
__global__ __launch_bounds__(256, 4)
void gram_k(const __hip_bfloat16* __restrict__ znT, float* __restrict__ G32)
{
    __shared__ unsigned short Asm[8192];   // 16 KB: 128 rows x 64 k, frag order
    __shared__ unsigned short Bsm[8192];
    const int tid = threadIdx.x, wave = tid >> 6, lane = tid & 63;
    const int f_l = lane & 15, q_l = lane >> 4;
    const int a0 = blockIdx.x * 128, b0 = blockIdx.y * 128;
    const int kbase = blockIdx.z * (NTOT / GKCH);
    const int wr = wave >> 1, wc = wave & 1;

    auto issue = [&](int k0) {
        #pragma unroll
        for (int s4 = 0; s4 < 4; ++s4) {
            const int seg = wave * 4 + s4, rowseg = seg >> 1, kh = seg & 1;
            const int gk  = kbase + k0 + kh * 32 + q_l * 8;
            const __hip_bfloat16* ga = znT + (size_t)(a0 + rowseg * 16 + f_l) * NTOT + gk;
            const __hip_bfloat16* gb = znT + (size_t)(b0 + rowseg * 16 + f_l) * NTOT + gk;
            __builtin_amdgcn_global_load_lds(
                (const __attribute__((address_space(1))) unsigned int*)ga,
                (__attribute__((address_space(3))) unsigned int*)(Asm + seg * 512 + lane * 8), 16, 0, 0);
            __builtin_amdgcn_global_load_lds(
                (const __attribute__((address_space(1))) unsigned int*)gb,
                (__attribute__((address_space(3))) unsigned int*)(Bsm + seg * 512 + lane * 8), 16, 0, 0);
        }
    };

    f32x4 acc[4][4];
    #pragma unroll
    for (int r = 0; r < 4; ++r)
        #pragma unroll
        for (int c = 0; c < 4; ++c) acc[r][c] = (f32x4){0.f,0.f,0.f,0.f};

    issue(0);
    for (int ki = 0; ki < NTOT / GKCH / 64; ++ki) {
        __syncthreads();
        bf16x8 af[4][2], bfr[4][2];
        #pragma unroll
        for (int r = 0; r < 4; ++r)
            #pragma unroll
            for (int h = 0; h < 2; ++h)
                af[r][h] = *(const bf16x8*)(Asm + ((wr*4+r)*2+h)*512 + lane*8);
        #pragma unroll
        for (int c = 0; c < 4; ++c)
            #pragma unroll
            for (int h = 0; h < 2; ++h)
                bfr[c][h] = *(const bf16x8*)(Bsm + ((wc*4+c)*2+h)*512 + lane*8);
        __syncthreads();
        if (ki < NTOT / GKCH / 64 - 1) issue((ki + 1) * 64);
        #pragma unroll
        for (int h = 0; h < 2; ++h)
            #pragma unroll
            for (int r = 0; r < 4; ++r)
                #pragma unroll
                for (int c = 0; c < 4; ++c)
                    acc[r][c] = __builtin_amdgcn_mfma_f32_16x16x32_bf16(af[r][h], bfr[c][h], acc[r][c], 0,0,0);
    }
    #pragma unroll
    for (int r = 0; r < 4; ++r)
        #pragma unroll
        for (int c = 0; c < 4; ++c)
            #pragma unroll
            for (int u = 0; u < 4; ++u)
                atomicAdd(&G32[(size_t)(a0 + wr*64 + r*16 + q_l*4 + u) * DIM
                               + b0 + wc*64 + c*16 + f_l], acc[r][c][u]);
}

// ---------------- qrowstat: Y-tile = Zn*G (B staged fp32->bf16 inline); ----------------
// epilogue accumulates q_i = sum_n Y[i][n]*zn[i][n], rowsum_i = sum_n zn[i][n]*S[n]
__global__ __launch_bounds__(256, 4)
void qrowstat_k(const __hip_bfloat16* __restrict__ zn,
                const float* __restrict__ G32,
                const float* __restrict__ S,
                float* __restrict__ rowsum,
                float* __restrict__ q)
{
    __shared__ unsigned short Asm[8192];
    __shared__ unsigned short Bsm[8192];
    const int tid = threadIdx.x, wave = tid >> 6, lane = tid & 63;
    const int f_l = lane & 15, q_l = lane >> 4;
    const int C0 = blockIdx.x * 128;   // dim slab (rows of G)
    const int R0 = blockIdx.y * 128;   // zn rows
    const int wr = wave >> 1, wc = wave & 1;

    auto issueA = [&](int k0) {
        #pragma unroll
        for (int s4 = 0; s4 < 4; ++s4) {
            const int seg = wave * 4 + s4, rowseg = seg >> 1, kh = seg & 1;
            const int gk  = k0 + kh * 32 + q_l * 8;
            const __hip_bfloat16* ga = zn + (size_t)(R0 + rowseg * 16 + f_l) * DIM + gk;
            __builtin_amdgcn_global_load_lds(
                (const __attribute__((address_space(1))) unsigned int*)ga,
                (__attribute__((address_space(3))) unsigned int*)(Asm + seg * 512 + lane * 8), 16, 0, 0);
        }
    };
    uint4 breg[4];
    auto loadB = [&](int k0) {
        #pragma unroll
        for (int s4 = 0; s4 < 4; ++s4) {
            const int seg = wave * 4 + s4, rowseg = seg >> 1, kh = seg & 1;
            const int gk  = k0 + kh * 32 + q_l * 8;
            const float* gp = G32 + (size_t)(C0 + rowseg * 16 + f_l) * DIM + gk;
            const float4 g0 = *(const float4*)gp;
            const float4 g1 = *(const float4*)(gp + 4);
            breg[s4].x = pack_bf16_2(g0.x, g0.y);
            breg[s4].y = pack_bf16_2(g0.z, g0.w);
            breg[s4].z = pack_bf16_2(g1.x, g1.y);
            breg[s4].w = pack_bf16_2(g1.z, g1.w);
        }
    };

    f32x4 acc[4][4];
    #pragma unroll
    for (int r = 0; r < 4; ++r)
        #pragma unroll
        for (int c = 0; c < 4; ++c) acc[r][c] = (f32x4){0.f,0.f,0.f,0.f};

    issueA(0);
    loadB(0);
    for (int ki = 0; ki < 8; ++ki) {
        #pragma unroll
        for (int s4 = 0; s4 < 4; ++s4)
            *(uint4*)(Bsm + (wave * 4 + s4) * 512 + lane * 8) = breg[s4];
        __syncthreads();
        bf16x8 af[4][2], bfr[4][2];
        #pragma unroll
        for (int r = 0; r < 4; ++r)
            #pragma unroll
            for (int h = 0; h < 2; ++h)
                af[r][h] = *(const bf16x8*)(Asm + ((wr*4+r)*2+h)*512 + lane*8);
        #pragma unroll
        for (int c = 0; c < 4; ++c)
            #pragma unroll
            for (int h = 0; h < 2; ++h)
                bfr[c][h] = *(const bf16x8*)(Bsm + ((wc*4+c)*2+h)*512 + lane*8);
        __syncthreads();
        if (ki < 7) { issueA((ki + 1) * 64); loadB((ki + 1) * 64); }
        #pragma unroll
        for (int h = 0; h < 2; ++h)
            #pragma unroll
            for (int r = 0; r < 4; ++r)
                #pragma unroll
                for (int c = 0; c < 4; ++c)
                    acc[r][c] = __builtin_amdgcn_mfma_f32_16x16x32_bf16(af[r][h], bfr[c][h], acc[r][c], 0,0,0);
    }

    // epilogue: per-row partial reductions (C/D: row = q_l*4+u, col = f_l)
    float Sn[4];
    #pragma unroll
    for (int c = 0; c < 4; ++c) Sn[c] = S[C0 + wc*64 + c*16 + f_l];
    #pragma unroll
    for (int r = 0; r < 4; ++r) {
        float qp[4] = {0,0,0,0}, rp[4] = {0,0,0,0};
        #pragma unroll
        for (int c = 0; c < 4; ++c) {
            const int n = C0 + wc*64 + c*16 + f_l;
            #pragma unroll
            for (int u = 0; u < 4; ++u) {
                const int i = R0 + wr*64 + r*16 + q_l*4 + u;
                const float w = __bfloat162float(zn[(size_t)i * DIM + n]);
                qp[u] += acc[r][c][u] * w;
                rp[u] += w * Sn[c];
            }
        }
        #pragma unroll
        for (int off = 1; off < 16; off <<= 1) {
            #pragma unroll
            for (int u = 0; u < 4; ++u) {
                qp[u] += __shfl_xor(qp[u], off);
                rp[u] += __shfl_xor(rp[u], off);
            }
        }
        if (f_l == 0) {
            #pragma unroll
            for (int u = 0; u < 4; ++u) {
                const int i = R0 + wr*64 + r*16 + q_l*4 + u;
                atomicAdd(&q[i], qp[u]);
                atomicAdd(&rowsum[i], rp[u]);
            }
        }
    }
}

// ---------------- sim pass: triangle MFMA, neg+pos in epilogue, last block -> loss ----------------
__global__ __launch_bounds__(256, 4)
void sim_neg_k(const __hip_bfloat16* __restrict__ zn,
               const int*   __restrict__ labels,
               const float* __restrict__ rowsum,
               const float* __restrict__ q,
               double* __restrict__ accs,          // [0]=neg, [1]=pos
               unsigned int* __restrict__ cnt,
               float* __restrict__ out)
{
    __shared__ unsigned short Asm[8192];   // 16 KB, frag order
    __shared__ unsigned short Bsm[8192];
    __shared__ float redbuf[8];
    const int tid = threadIdx.x, wave = tid >> 6, lane = tid & 63;
    const int f_l = lane & 15, q_l = lane >> 4;
    int bi, bj;
    decode_tile(blockIdx.x, bi, bj);
    const int R0 = bi * 128, C0 = bj * 128;
    const int wr = wave >> 1, wc = wave & 1;
    const bool posTile = (bj == bi + 32);   // contains pairs (i, i+4096) on its diagonal

    auto issue = [&](int k0) {
        #pragma unroll
        for (int s4 = 0; s4 < 4; ++s4) {
            const int seg = wave * 4 + s4, rowseg = seg >> 1, kh = seg & 1;
            const int gk  = k0 + kh * 32 + q_l * 8;
            const __hip_bfloat16* ga = zn + (size_t)(R0 + rowseg * 16 + f_l) * DIM + gk;
            const __hip_bfloat16* gb = zn + (size_t)(C0 + rowseg * 16 + f_l) * DIM + gk;
            __builtin_amdgcn_global_load_lds(
                (const __attribute__((address_space(1))) unsigned int*)ga,
                (__attribute__((address_space(3))) unsigned int*)(Asm + seg * 512 + lane * 8), 16, 0, 0);
            __builtin_amdgcn_global_load_lds(
                (const __attribute__((address_space(1))) unsigned int*)gb,
                (__attribute__((address_space(3))) unsigned int*)(Bsm + seg * 512 + lane * 8), 16, 0, 0);
        }
    };

    f32x4 acc[4][4];
    #pragma unroll
    for (int r = 0; r < 4; ++r)
        #pragma unroll
        for (int c = 0; c < 4; ++c) acc[r][c] = (f32x4){0.f,0.f,0.f,0.f};

    issue(0);
    for (int ki = 0; ki < 8; ++ki) {
        __syncthreads();
        bf16x8 af[4][2], bfr[4][2];
        #pragma unroll
        for (int r = 0; r < 4; ++r)
            #pragma unroll
            for (int h = 0; h < 2; ++h)
                af[r][h] = *(const bf16x8*)(Asm + ((wr*4+r)*2+h)*512 + lane*8);
        #pragma unroll
        for (int c = 0; c < 4; ++c)
            #pragma unroll
            for (int h = 0; h < 2; ++h)
                bfr[c][h] = *(const bf16x8*)(Bsm + ((wc*4+c)*2+h)*512 + lane*8);
        __syncthreads();
        if (ki < 7) issue((ki + 1) * 64);
        #pragma unroll
        for (int h = 0; h < 2; ++h)
            #pragma unroll
            for (int r = 0; r < 4; ++r)
                #pragma unroll
                for (int c = 0; c < 4; ++c)
                    acc[r][c] = __builtin_amdgcn_mfma_f32_16x16x32_bf16(af[r][h], bfr[c][h], acc[r][c], 0,0,0);
    }

    // stats inline: mu = 1 - rowsum/N ; inv2s2 = 1/(2*(q - rowsum^2/N)/(N-1))
    int labj[4]; float muj[4], isj[4];
    #pragma unroll
    for (int c = 0; c < 4; ++c) {
        const int j = C0 + wc*64 + c*16 + f_l;
        labj[c] = labels[j];
        const float rs = rowsum[j], qq = q[j];
        const float mean = rs * (1.0f / NTOT);
        const float var  = (qq - rs * mean) * (1.0f / (NTOT - 1));
        muj[c] = 1.0f - mean;
        isj[c] = 1.0f / (2.0f * var);
    }
    float local = 0.f, posl = 0.f;
    #pragma unroll
    for (int r = 0; r < 4; ++r) {
        const int ib = R0 + wr*64 + r*16 + q_l*4;
        int   li[4]; float mi[4], vi[4];
        #pragma unroll
        for (int u = 0; u < 4; ++u) {
            li[u] = labels[ib + u];
            const float rs = rowsum[ib + u], qq = q[ib + u];
            const float mean = rs * (1.0f / NTOT);
            const float var  = (qq - rs * mean) * (1.0f / (NTOT - 1));
            mi[u] = 1.0f - mean;
            vi[u] = 1.0f / (2.0f * var);
        }
        #pragma unroll
        for (int u = 0; u < 4; ++u) {
            const int irow = wr*64 + r*16 + q_l*4 + u;
            #pragma unroll
            for (int c = 0; c < 4; ++c) {
                const int jcol = wc*64 + c*16 + f_l;
                const float s  = acc[r][c][u];
                const float d  = 1.0f - s;
                const float dj = d - muj[c];
                float e = __expf(s * TEMP_INV + dj * dj * isj[c]);
                if (bi != bj) {                    // wave-uniform
                    const float di = d - mi[u];
                    e += __expf(s * TEMP_INV + di * di * vi[u]);
                }
                local += (li[u] != labj[c]) ? e : 0.f;
                if (posTile && irow == jcol && li[u] == labj[c])
                    posl += __expf(s * TEMP_INV);
            }
        }
    }
    #pragma unroll
    for (int off = 1; off < 64; off <<= 1) {
        local += __shfl_xor(local, off);
        posl  += __shfl_xor(posl, off);
    }
    if (lane == 0) { redbuf[wave] = local; redbuf[4 + wave] = posl; }
    __syncthreads();
    if (tid == 0) {
        atomicAdd(&accs[0], (double)(redbuf[0] + redbuf[1] + redbuf[2] + redbuf[3]));
        if (posTile)
            atomicAdd(&accs[1], (double)(redbuf[4] + redbuf[5] + redbuf[6] + redbuf[7]));
        __threadfence();
        const unsigned int done = atomicAdd(cnt, 1u);
        if (done == NBLK - 1) {
            const double neg = atomicAdd(&accs[0], 0.0);
            const double pos = atomicAdd(&accs[1], 0.0);
            out[0] = (float)(-log(pos / (pos + neg)));
        }
    }
}

extern "C" void kernel_launch(void* const* d_in, const int* in_sizes, int n_in,
                              void* d_out, int out_size, void* d_ws, size_t ws_size,
                              hipStream_t stream)
{
    const float* z      = (const float*)d_in[0];
    const int*   labels = (const int*)d_in[1];
    float* out = (float*)d_out;

    char* ws = (char*)d_ws;
    __hip_bfloat16* zn  = (__hip_bfloat16*)ws;                       // 8 MiB
    const size_t ZN_BYTES = (size_t)NTOT * DIM * 2;
    __hip_bfloat16* znT = (__hip_bfloat16*)(ws + ZN_BYTES);          // 8 MiB
    char* p = ws + 2 * ZN_BYTES;
    float*        S      = (float*)p;        p += DIM * sizeof(float);       // 2 KB
    double*       accs   = (double*)p;       p += 2 * sizeof(double);        // 16 B
    unsigned int* cnt    = (unsigned int*)p; p += 16;                        // 16 B (pad)
    float*        rowsum = (float*)p;        p += NTOT * sizeof(float);      // 32 KB
    float*        q      = (float*)p;        p += NTOT * sizeof(float);      // 32 KB
    float*        G32    = (float*)p;        // 1 MiB

    const size_t ZERO_BYTES = DIM * sizeof(float) + 16 + 16
                            + 2 * NTOT * sizeof(float)
                            + (size_t)DIM * DIM * sizeof(float);
    hipMemsetAsync(S, 0, ZERO_BYTES, stream);

    norm_trans_k<<<NTOT / 32, 256, 0, stream>>>(z, zn, znT, S);
    gram_k<<<dim3(4, 4, GKCH), 256, 0, stream>>>(znT, G32);
    qrowstat_k<<<dim3(DIM / 128, NTOT / 128), 256, 0, stream>>>(zn, G32, S, rowsum, q);
    sim_neg_k<<<NBLK, 256, 0, stream>>>(zn, labels, rowsum, q, accs, cnt, out);
}